// Round 6
// baseline (756.733 us; speedup 1.0000x reference)
//
#include <hip/hip_runtime.h>
#include <hip/hip_bf16.h>

typedef __attribute__((ext_vector_type(8))) short short8;
typedef __attribute__((ext_vector_type(4))) short short4v;
typedef __attribute__((ext_vector_type(4))) float f32x4;

#define MFMA(a, b, c) __builtin_amdgcn_mfma_f32_16x16x32_bf16(a, b, c, 0, 0, 0)
// XOR-swizzled [64][256] bf16 LDS index (8-elem granule)
#define XS(t, c) (((t) << 8) + ((c) ^ (((t) & 7) << 3)))
// XOR-swizzled [64][128] bf16 LDS index (8-elem granule over 16 chunks)
#define XO(t, c) (((t) << 7) + (((((c) >> 3) ^ ((t) & 7)) << 3) | ((c) & 7)))

__device__ __forceinline__ unsigned int pk2(float lo, float hi) {
    union { __hip_bfloat162 h2; unsigned int u; } cv;
    cv.h2 = __float22bfloat162_rn(make_float2(lo, hi));
    return cv.u;
}

__device__ __forceinline__ unsigned short f2bf1(float f) {
    unsigned int u = __float_as_uint(f);
    u += 0x7FFFu + ((u >> 16) & 1u);
    return (unsigned short)(u >> 16);
}

__device__ __forceinline__ short4v u2s4(uint2 p) {
    union { uint2 u; short4v s; } t; t.u = p; return t.s;
}

#if __has_builtin(__builtin_amdgcn_mfma_f32_16x16x16bf16_1k)
__device__ __forceinline__ f32x4 mfma16(uint2 a, uint2 b, f32x4 c) {
    return __builtin_amdgcn_mfma_f32_16x16x16bf16_1k(u2s4(a), u2s4(b), c, 0, 0, 0);
}
#else
__device__ __forceinline__ short8 zfrag(uint2 p) {
    union { unsigned int u[4]; short8 s; } t;
    t.u[0] = p.x; t.u[1] = p.y; t.u[2] = 0u; t.u[3] = 0u;
    return t.s;
}
__device__ __forceinline__ f32x4 mfma16(uint2 a, uint2 b, f32x4 c) {
    return MFMA(zfrag(a), zfrag(b), c);
}
#endif

#define EXP2(x) exp2f(x)

// d_ws: [0..196608) wqkvT bf16 [768][256]; [196608..262144) wprojT [256][256];
//       [262144 .. +67108864 elems) O bf16 [262144 tok (SPATIAL order)][256 ch]
__global__ void prep_w(const float* __restrict__ wqkv, const float* __restrict__ wproj,
                       unsigned short* __restrict__ wT) {
    int idx = blockIdx.x * 256 + threadIdx.x;
    if (idx < 768 * 256) {
        int n = idx >> 8, k = idx & 255;
        wT[idx] = f2bf1(wqkv[k * 768 + n]);
    } else {
        int r = idx - 768 * 256;
        int n = r >> 8, k = r & 255;
        wT[idx] = f2bf1(wproj[(k << 8) + n]);
    }
}

// ============ Kernel A: per (window, head-quad) QKV + attention ============
__global__ __launch_bounds__(256, 4)
void attn_qkv(const float* __restrict__ x,
              const float* __restrict__ bqkv,
              const unsigned short* __restrict__ wqkvT,
              unsigned short* __restrict__ Ob)
{
    __shared__ unsigned short smem[64 * 256];   // 32 KiB: x, then O-half overlay

    const int tid  = threadIdx.x;
    const int wid  = tid >> 6;
    const int lane = tid & 63;
    const int g    = lane >> 4;
    const int q16  = lane & 15;

    // XCD-pairing swizzle: pair (hq=0, hq=4) of a window lands on the same XCD,
    // 8 apart in dispatch order -> x-window L2 reuse.
    const int bid  = blockIdx.x;
    const int xcd  = bid & 7;
    const int q    = bid >> 3;
    const int widx = xcd * 512 + (q >> 1);
    const int hq   = (q & 1) << 2;     // head-quad base (0 or 4)
    const int h    = hq + wid;         // this wave's head

    const int b  = widx >> 10;
    const int wh = (widx >> 5) & 31;
    const int ww = widx & 31;

    // ---- stage x window -> LDS bf16 (swizzled) ----
    {
        const int t  = tid >> 2;           // token 0..63
        const int c0 = (tid & 3) << 3;     // channel base
        const int hr = (wh << 3) + (t >> 3);
        const int wc = (ww << 3) + (t & 7);
        const float* rowp = x + (((size_t)b * 256 + hr) * 256 + wc) * 256;
        #pragma unroll
        for (int u = 0; u < 8; ++u) {
            const int c = c0 + (u << 5);
            const float4 f0 = *reinterpret_cast<const float4*>(rowp + c);
            const float4 f1 = *reinterpret_cast<const float4*>(rowp + c + 4);
            union { unsigned int u4[4]; short8 s; } pv;
            pv.u4[0] = pk2(f0.x, f0.y); pv.u4[1] = pk2(f0.z, f0.w);
            pv.u4[2] = pk2(f1.x, f1.y); pv.u4[3] = pk2(f1.z, f1.w);
            *reinterpret_cast<short8*>(&smem[XS(t, c)]) = pv.s;
        }
    }
    __syncthreads();

    const f32x4 fz = {0.f, 0.f, 0.f, 0.f};
    const float SCL = 0.17677669529663687f * 1.4426950408889634f;  // scale*log2e

    // ===== QKV, m-major =====
    uint2 pk[3][2][4];
    #pragma unroll
    for (int m = 0; m < 3; ++m) {
        f32x4 acc[2][4];
        #pragma unroll
        for (int dt = 0; dt < 2; ++dt)
            #pragma unroll
            for (int tt = 0; tt < 4; ++tt) acc[dt][tt] = fz;

        const unsigned short* wb = wqkvT + (size_t)(m * 256 + h * 32) * 256;
        #pragma unroll
        for (int ks = 0; ks < 8; ++ks) {
            const int kc = ks << 5;
            short8 xf[4];
            #pragma unroll
            for (int tt = 0; tt < 4; ++tt)
                xf[tt] = *reinterpret_cast<const short8*>(&smem[XS(tt * 16 + q16, kc + (g << 3))]);
            #pragma unroll
            for (int dt = 0; dt < 2; ++dt) {
                const short8 wf = *reinterpret_cast<const short8*>(
                    wb + (size_t)(dt * 16 + q16) * 256 + kc + (g << 3));
                #pragma unroll
                for (int tt = 0; tt < 4; ++tt)
                    acc[dt][tt] = (m < 2) ? MFMA(wf, xf[tt], acc[dt][tt])
                                          : MFMA(xf[tt], wf, acc[dt][tt]);
            }
        }
        if (m < 2) {
            #pragma unroll
            for (int dt = 0; dt < 2; ++dt) {
                const float4 bb = *reinterpret_cast<const float4*>(
                    bqkv + m * 256 + h * 32 + dt * 16 + (g << 2));
                const float sc = (m == 0) ? SCL : 1.f;
                #pragma unroll
                for (int tt = 0; tt < 4; ++tt) {
                    const f32x4 a = acc[dt][tt];
                    pk[m][dt][tt] = make_uint2(pk2((a[0] + bb.x) * sc, (a[1] + bb.y) * sc),
                                               pk2((a[2] + bb.z) * sc, (a[3] + bb.w) * sc));
                }
            }
        } else {
            #pragma unroll
            for (int dt = 0; dt < 2; ++dt) {
                const float bv = bqkv[512 + h * 32 + dt * 16 + q16];
                #pragma unroll
                for (int tt = 0; tt < 4; ++tt) {
                    const f32x4 a = acc[dt][tt];
                    pk[2][dt][tt] = make_uint2(pk2(a[0] + bv, a[1] + bv),
                                               pk2(a[2] + bv, a[3] + bv));
                }
            }
        }
    }

    // ===== S^T = K·Q^T (K=16), exp2 (no max-sub), unnormalized P^T =====
    uint2 ppk[4][4];
    float inv4[4];
    #pragma unroll
    for (int qt = 0; qt < 4; ++qt) {
        f32x4 st[4];
        #pragma unroll
        for (int kt = 0; kt < 4; ++kt) st[kt] = fz;
        #pragma unroll
        for (int dt = 0; dt < 2; ++dt)
            #pragma unroll
            for (int kt = 0; kt < 4; ++kt)
                st[kt] = mfma16(pk[1][dt][kt], pk[0][dt][qt], st[kt]);
        float sum = 0.f;
        #pragma unroll
        for (int kt = 0; kt < 4; ++kt) {
            const float e0 = EXP2(st[kt][0]), e1 = EXP2(st[kt][1]);
            const float e2 = EXP2(st[kt][2]), e3 = EXP2(st[kt][3]);
            sum += (e0 + e1) + (e2 + e3);
            ppk[kt][qt] = make_uint2(pk2(e0, e1), pk2(e2, e3));
        }
        sum += __shfl_xor(sum, 16);
        sum += __shfl_xor(sum, 32);
        inv4[qt] = 1.f / sum;
    }

    // ===== O^T = V^T·P^T (K=16) =====
    f32x4 ot[2][4];
    #pragma unroll
    for (int dt = 0; dt < 2; ++dt)
        #pragma unroll
        for (int tt = 0; tt < 4; ++tt) ot[dt][tt] = fz;
    #pragma unroll
    for (int kt = 0; kt < 4; ++kt)
        #pragma unroll
        for (int tt = 0; tt < 4; ++tt)
            #pragma unroll
            for (int dt = 0; dt < 2; ++dt)
                ot[dt][tt] = mfma16(pk[2][dt][kt], ppk[kt][tt], ot[dt][tt]);

    __syncthreads();   // all waves' x reads done before O overlay
    // O overlay write: [64 tok][128 ch] swizzled, ch = wid*32 + dt*16 + g*4
    #pragma unroll
    for (int dt = 0; dt < 2; ++dt)
        #pragma unroll
        for (int tt = 0; tt < 4; ++tt) {
            const float iv = inv4[tt];
            const int tok = tt * 16 + q16;
            const int c   = wid * 32 + dt * 16 + (g << 2);
            const uint2 pv = make_uint2(pk2(ot[dt][tt][0] * iv, ot[dt][tt][1] * iv),
                                        pk2(ot[dt][tt][2] * iv, ot[dt][tt][3] * iv));
            *reinterpret_cast<uint2*>(&smem[XO(tok, c)]) = pv;
        }
    __syncthreads();

    // ---- copy O-half (16KB) LDS -> Ob in SPATIAL row order ----
    // spatial row = ((b*256 + wh*8 + tr) * 256 + ww*8 + tc); proj reads/writes same order
    {
        const int t = tid >> 2;
        const int j = tid & 3;
        const size_t srow = (((size_t)(b << 8) + (wh << 3) + (t >> 3)) << 8)
                            + (ww << 3) + (t & 7);
        unsigned short* dst = Ob + (srow << 8) + (hq << 5);
        #pragma unroll
        for (int i = 0; i < 4; ++i) {
            const int cc = (j << 2) + i;   // chunk 0..15 (8 bf16 each)
            const uint4 v = *reinterpret_cast<const uint4*>(&smem[XO(t, cc << 3)]);
            *reinterpret_cast<uint4*>(dst + (cc << 3)) = v;
        }
    }
}

// ============ Kernel B: proj GEMM  out = O @ wproj + bias ============
__global__ __launch_bounds__(256, 4)
void proj_gemm(const unsigned short* __restrict__ Ob,
               const unsigned short* __restrict__ wprojT,
               const float* __restrict__ bproj,
               float* __restrict__ out)
{
    __shared__ unsigned short As[2][128 * 64];   // 16KB each
    __shared__ unsigned short Bs[2][128 * 64];

    const int tid  = threadIdx.x;
    const int wid  = tid >> 6;
    const int lane = tid & 63;
    const int g    = lane >> 4;
    const int q16  = lane & 15;
    const int wr   = wid >> 1, wc = wid & 1;

    // XCD-pairing swizzle: (mt, nt=0/1) pair shares the A-tile on one XCD
    const int bid = blockIdx.x;
    const int q   = bid >> 3;
    const int mt  = (bid & 7) * 256 + (q >> 1);
    const int nt  = q & 1;
    const size_t mrow0 = (size_t)mt << 7;
    const int nrow0 = nt << 7;

    const f32x4 fz = {0.f, 0.f, 0.f, 0.f};
    f32x4 acc[4][4];
    #pragma unroll
    for (int i = 0; i < 4; ++i)
        #pragma unroll
        for (int j = 0; j < 4; ++j) acc[i][j] = fz;

    int buf = 0;
    // prologue stage s=0
    #pragma unroll
    for (int i = 0; i < 4; ++i) {
        const int chunk = (i << 8) + tid;
        const int r = chunk >> 3, c = chunk & 7;
        const int cs = c ^ (r & 7);
        const uint4 va = *reinterpret_cast<const uint4*>(Ob + ((mrow0 + r) << 8) + (c << 3));
        *reinterpret_cast<uint4*>(&As[0][(r << 6) + (cs << 3)]) = va;
        const uint4 vb = *reinterpret_cast<const uint4*>(wprojT + ((size_t)(nrow0 + r) << 8) + (c << 3));
        *reinterpret_cast<uint4*>(&Bs[0][(r << 6) + (cs << 3)]) = vb;
    }
    __syncthreads();

    for (int s = 0; s < 4; ++s) {
        if (s < 3) {
            const int so = (s + 1) << 6;
            #pragma unroll
            for (int i = 0; i < 4; ++i) {
                const int chunk = (i << 8) + tid;
                const int r = chunk >> 3, c = chunk & 7;
                const int cs = c ^ (r & 7);
                const uint4 va = *reinterpret_cast<const uint4*>(Ob + ((mrow0 + r) << 8) + so + (c << 3));
                *reinterpret_cast<uint4*>(&As[buf ^ 1][(r << 6) + (cs << 3)]) = va;
                const uint4 vb = *reinterpret_cast<const uint4*>(wprojT + ((size_t)(nrow0 + r) << 8) + so + (c << 3));
                *reinterpret_cast<uint4*>(&Bs[buf ^ 1][(r << 6) + (cs << 3)]) = vb;
            }
        }
        #pragma unroll
        for (int kk = 0; kk < 2; ++kk) {
            short8 aF[4], bF[4];
            #pragma unroll
            for (int i = 0; i < 4; ++i) {
                const int rA = (wr << 6) + (i << 4) + q16;
                const int cA = ((kk << 2) + g) ^ (rA & 7);
                aF[i] = *reinterpret_cast<const short8*>(&As[buf][(rA << 6) + (cA << 3)]);
                const int rB = (wc << 6) + (i << 4) + q16;
                const int cB = ((kk << 2) + g) ^ (rB & 7);
                bF[i] = *reinterpret_cast<const short8*>(&Bs[buf][(rB << 6) + (cB << 3)]);
            }
            #pragma unroll
            for (int i = 0; i < 4; ++i)
                #pragma unroll
                for (int j = 0; j < 4; ++j)
                    acc[i][j] = MFMA(aF[i], bF[j], acc[i][j]);
        }
        __syncthreads();
        buf ^= 1;
    }

    // epilogue: rows are spatial order -> direct coalesced store
    #pragma unroll
    for (int j = 0; j < 4; ++j) {
        const int coln = nrow0 + (wc << 6) + (j << 4) + q16;
        const float bp = bproj[coln];
        #pragma unroll
        for (int i = 0; i < 4; ++i) {
            const size_t row = mrow0 + (wr << 6) + (i << 4) + (g << 2);
            #pragma unroll
            for (int rr = 0; rr < 4; ++rr)
                out[((row + rr) << 8) + coln] = acc[i][j][rr] + bp;
        }
    }
}

// ============ Fallback: R4 fused kernel (if ws too small) ============
__global__ __launch_bounds__(512, 2)
void winattn_fused(const float* __restrict__ x,
                   const float* __restrict__ bqkv,
                   const float* __restrict__ bproj,
                   const unsigned short* __restrict__ wqkvT,
                   const unsigned short* __restrict__ wprojT,
                   float* __restrict__ out)
{
    __shared__ unsigned short smem[64 * 256];

    const int tid  = threadIdx.x;
    const int h    = tid >> 6;
    const int lane = tid & 63;
    const int g    = lane >> 4;
    const int q16  = lane & 15;

    const int widx = blockIdx.x;
    const int b  = widx >> 10;
    const int wh = (widx >> 5) & 31;
    const int ww = widx & 31;

    {
        const int t  = tid >> 3;
        const int c0 = (tid & 7) << 3;
        const int hr = (wh << 3) + (t >> 3);
        const int wc = (ww << 3) + (t & 7);
        const float* rowp = x + (((size_t)b * 256 + hr) * 256 + wc) * 256;
        #pragma unroll
        for (int u = 0; u < 4; ++u) {
            const int c = c0 + (u << 6);
            const float4 f0 = *reinterpret_cast<const float4*>(rowp + c);
            const float4 f1 = *reinterpret_cast<const float4*>(rowp + c + 4);
            union { unsigned int u4[4]; short8 s; } pv;
            pv.u4[0] = pk2(f0.x, f0.y); pv.u4[1] = pk2(f0.z, f0.w);
            pv.u4[2] = pk2(f1.x, f1.y); pv.u4[3] = pk2(f1.z, f1.w);
            *reinterpret_cast<short8*>(&smem[XS(t, c)]) = pv.s;
        }
    }
    __syncthreads();

    const f32x4 fz = {0.f, 0.f, 0.f, 0.f};
    const float SCL = 0.17677669529663687f * 1.4426950408889634f;

    uint2 pk[3][2][4];
    #pragma unroll
    for (int m = 0; m < 3; ++m) {
        f32x4 acc[2][4];
        #pragma unroll
        for (int dt = 0; dt < 2; ++dt)
            #pragma unroll
            for (int tt = 0; tt < 4; ++tt) acc[dt][tt] = fz;
        const unsigned short* wb = wqkvT + (size_t)(m * 256 + h * 32) * 256;
        #pragma unroll
        for (int ks = 0; ks < 8; ++ks) {
            const int kc = ks << 5;
            short8 xf[4];
            #pragma unroll
            for (int tt = 0; tt < 4; ++tt)
                xf[tt] = *reinterpret_cast<const short8*>(&smem[XS(tt * 16 + q16, kc + (g << 3))]);
            #pragma unroll
            for (int dt = 0; dt < 2; ++dt) {
                const short8 wf = *reinterpret_cast<const short8*>(
                    wb + (size_t)(dt * 16 + q16) * 256 + kc + (g << 3));
                #pragma unroll
                for (int tt = 0; tt < 4; ++tt)
                    acc[dt][tt] = (m < 2) ? MFMA(wf, xf[tt], acc[dt][tt])
                                          : MFMA(xf[tt], wf, acc[dt][tt]);
            }
        }
        if (m < 2) {
            #pragma unroll
            for (int dt = 0; dt < 2; ++dt) {
                const float4 bb = *reinterpret_cast<const float4*>(
                    bqkv + m * 256 + h * 32 + dt * 16 + (g << 2));
                const float sc = (m == 0) ? SCL : 1.f;
                #pragma unroll
                for (int tt = 0; tt < 4; ++tt) {
                    const f32x4 a = acc[dt][tt];
                    pk[m][dt][tt] = make_uint2(pk2((a[0] + bb.x) * sc, (a[1] + bb.y) * sc),
                                               pk2((a[2] + bb.z) * sc, (a[3] + bb.w) * sc));
                }
            }
        } else {
            #pragma unroll
            for (int dt = 0; dt < 2; ++dt) {
                const float bv = bqkv[512 + h * 32 + dt * 16 + q16];
                #pragma unroll
                for (int tt = 0; tt < 4; ++tt) {
                    const f32x4 a = acc[dt][tt];
                    pk[2][dt][tt] = make_uint2(pk2(a[0] + bv, a[1] + bv),
                                               pk2(a[2] + bv, a[3] + bv));
                }
            }
        }
    }

    uint2 ppk[4][4];
    float inv4[4];
    #pragma unroll
    for (int qt = 0; qt < 4; ++qt) {
        f32x4 st[4];
        #pragma unroll
        for (int kt = 0; kt < 4; ++kt) st[kt] = fz;
        #pragma unroll
        for (int dt = 0; dt < 2; ++dt)
            #pragma unroll
            for (int kt = 0; kt < 4; ++kt)
                st[kt] = mfma16(pk[1][dt][kt], pk[0][dt][qt], st[kt]);
        float sum = 0.f;
        #pragma unroll
        for (int kt = 0; kt < 4; ++kt) {
            const float e0 = EXP2(st[kt][0]), e1 = EXP2(st[kt][1]);
            const float e2 = EXP2(st[kt][2]), e3 = EXP2(st[kt][3]);
            sum += (e0 + e1) + (e2 + e3);
            ppk[kt][qt] = make_uint2(pk2(e0, e1), pk2(e2, e3));
        }
        sum += __shfl_xor(sum, 16);
        sum += __shfl_xor(sum, 32);
        inv4[qt] = 1.f / sum;
    }

    f32x4 ot[2][4];
    #pragma unroll
    for (int dt = 0; dt < 2; ++dt)
        #pragma unroll
        for (int tt = 0; tt < 4; ++tt) ot[dt][tt] = fz;
    #pragma unroll
    for (int kt = 0; kt < 4; ++kt)
        #pragma unroll
        for (int tt = 0; tt < 4; ++tt)
            #pragma unroll
            for (int dt = 0; dt < 2; ++dt)
                ot[dt][tt] = mfma16(pk[2][dt][kt], ppk[kt][tt], ot[dt][tt]);

    __syncthreads();
    #pragma unroll
    for (int dt = 0; dt < 2; ++dt)
        #pragma unroll
        for (int tt = 0; tt < 4; ++tt) {
            const float iv = inv4[tt];
            const int tok = tt * 16 + q16;
            const int d   = h * 32 + dt * 16 + (g << 2);
            const uint2 pv = make_uint2(pk2(ot[dt][tt][0] * iv, ot[dt][tt][1] * iv),
                                        pk2(ot[dt][tt][2] * iv, ot[dt][tt][3] * iv));
            *reinterpret_cast<uint2*>(&smem[XS(tok, d)]) = pv;
        }
    __syncthreads();

    f32x4 pacc[4][2];
    #pragma unroll
    for (int mt = 0; mt < 4; ++mt)
        #pragma unroll
        for (int nt = 0; nt < 2; ++nt) pacc[mt][nt] = fz;
    #pragma unroll
    for (int ks = 0; ks < 8; ++ks) {
        const int kc = ks << 5;
        short8 of[4], wf[2];
        #pragma unroll
        for (int mt = 0; mt < 4; ++mt)
            of[mt] = *reinterpret_cast<const short8*>(&smem[XS(mt * 16 + q16, kc + (g << 3))]);
        #pragma unroll
        for (int nt = 0; nt < 2; ++nt)
            wf[nt] = *reinterpret_cast<const short8*>(
                wprojT + (size_t)(h * 32 + nt * 16 + q16) * 256 + kc + (g << 3));
        #pragma unroll
        for (int mt = 0; mt < 4; ++mt)
            #pragma unroll
            for (int nt = 0; nt < 2; ++nt)
                pacc[mt][nt] = MFMA(of[mt], wf[nt], pacc[mt][nt]);
    }
    {
        float bp[2];
        #pragma unroll
        for (int nt = 0; nt < 2; ++nt) bp[nt] = bproj[h * 32 + nt * 16 + q16];
        float* obase = out + (((size_t)b * 256 + (wh << 3) + (g >> 1)) * 256
                              + (ww << 3) + ((g & 1) << 2)) * 256 + h * 32 + q16;
        #pragma unroll
        for (int mt = 0; mt < 4; ++mt)
            #pragma unroll
            for (int r = 0; r < 4; ++r)
                #pragma unroll
                for (int nt = 0; nt < 2; ++nt)
                    obase[mt * 131072 + r * 256 + nt * 16] = pacc[mt][nt][r] + bp[nt];
    }
}

extern "C" void kernel_launch(void* const* d_in, const int* in_sizes, int n_in,
                              void* d_out, int out_size, void* d_ws, size_t ws_size,
                              hipStream_t stream) {
    const float* x     = (const float*)d_in[0];
    const float* wqkv  = (const float*)d_in[1];
    const float* bqkv  = (const float*)d_in[2];
    const float* wproj = (const float*)d_in[3];
    const float* bproj = (const float*)d_in[4];
    float* out = (float*)d_out;
    unsigned short* wT = (unsigned short*)d_ws;

    prep_w<<<1024, 256, 0, stream>>>(wqkv, wproj, wT);

    const size_t need = 524288ull + 262144ull * 256ull * 2ull;  // weights + O
    if (ws_size >= need) {
        unsigned short* Ob = wT + 262144;   // byte offset 524288
        attn_qkv<<<8192, 256, 0, stream>>>(x, bqkv, wT, Ob);
        proj_gemm<<<4096, 256, 0, stream>>>(Ob, wT + 768 * 256, bproj, out);
    } else {
        winattn_fused<<<4096, 512, 0, stream>>>(x, bqkv, bproj, wT, wT + 768 * 256, out);
    }
}

// Round 7
// 403.483 us; speedup vs baseline: 1.8755x; 1.8755x over previous
//
#include <hip/hip_runtime.h>
#include <hip/hip_bf16.h>

typedef __attribute__((ext_vector_type(8))) short short8;
typedef __attribute__((ext_vector_type(4))) short short4v;
typedef __attribute__((ext_vector_type(4))) float f32x4;

#define MFMA(a, b, c) __builtin_amdgcn_mfma_f32_16x16x32_bf16(a, b, c, 0, 0, 0)
// XOR-swizzled [64][256] bf16 LDS index (8-elem granule)
#define XS(t, c) (((t) << 8) + ((c) ^ (((t) & 7) << 3)))

__device__ __forceinline__ unsigned int pk2(float lo, float hi) {
    union { __hip_bfloat162 h2; unsigned int u; } cv;
    cv.h2 = __float22bfloat162_rn(make_float2(lo, hi));
    return cv.u;
}

__device__ __forceinline__ unsigned short f2bf1(float f) {
    unsigned int u = __float_as_uint(f);
    u += 0x7FFFu + ((u >> 16) & 1u);
    return (unsigned short)(u >> 16);
}

__device__ __forceinline__ short4v u2s4(uint2 p) {
    union { uint2 u; short4v s; } t; t.u = p; return t.s;
}

#if __has_builtin(__builtin_amdgcn_mfma_f32_16x16x16bf16_1k)
__device__ __forceinline__ f32x4 mfma16(uint2 a, uint2 b, f32x4 c) {
    return __builtin_amdgcn_mfma_f32_16x16x16bf16_1k(u2s4(a), u2s4(b), c, 0, 0, 0);
}
#else
__device__ __forceinline__ short8 zfrag(uint2 p) {
    union { unsigned int u[4]; short8 s; } t;
    t.u[0] = p.x; t.u[1] = p.y; t.u[2] = 0u; t.u[3] = 0u;
    return t.s;
}
__device__ __forceinline__ f32x4 mfma16(uint2 a, uint2 b, f32x4 c) {
    return MFMA(zfrag(a), zfrag(b), c);
}
#endif

#define EXP2(x) exp2f(x)

// d_ws: [0..196608) wqkvT bf16 [768][256]; [196608..262144) wprojT [256][256];
//       [262144 .. +67108864 elems) O bf16 [262144 tok (SPATIAL order)][256 ch]
__global__ void prep_w(const float* __restrict__ wqkv, const float* __restrict__ wproj,
                       unsigned short* __restrict__ wT) {
    int idx = blockIdx.x * 256 + threadIdx.x;
    if (idx < 768 * 256) {
        int n = idx >> 8, k = idx & 255;
        wT[idx] = f2bf1(wqkv[k * 768 + n]);
    } else {
        int r = idx - 768 * 256;
        int n = r >> 8, k = r & 255;
        wT[idx] = f2bf1(wproj[(k << 8) + n]);
    }
}

// ============ Kernel A: per (window, head-quad) QKV + attention ============
// launch_bounds(…, 2): empirical VGPR cap = 128 (arg=4 caps at 64 -> spill disaster)
__global__ __launch_bounds__(256, 2)
void attn_qkv(const float* __restrict__ x,
              const float* __restrict__ bqkv,
              const unsigned short* __restrict__ wqkvT,
              unsigned short* __restrict__ Ob)
{
    __shared__ unsigned short smem[64 * 256];   // 32 KiB: x only

    const int tid  = threadIdx.x;
    const int wid  = tid >> 6;
    const int lane = tid & 63;
    const int g    = lane >> 4;
    const int q16  = lane & 15;

    // XCD-pairing swizzle: the two head-quad blocks of a window land on the
    // same XCD, 8 apart in dispatch -> x-window L2 reuse.
    const int bid  = blockIdx.x;
    const int xcd  = bid & 7;
    const int q    = bid >> 3;
    const int widx = xcd * 512 + (q >> 1);
    const int hq   = (q & 1) << 2;     // head-quad base (0 or 4)
    const int h    = hq + wid;         // this wave's head

    const int b  = widx >> 10;
    const int wh = (widx >> 5) & 31;
    const int ww = widx & 31;

    // ---- stage x window -> LDS bf16 (swizzled) ----
    {
        const int t  = tid >> 2;           // token 0..63
        const int c0 = (tid & 3) << 3;     // channel base
        const int hr = (wh << 3) + (t >> 3);
        const int wc = (ww << 3) + (t & 7);
        const float* rowp = x + (((size_t)b * 256 + hr) * 256 + wc) * 256;
        #pragma unroll
        for (int u = 0; u < 8; ++u) {
            const int c = c0 + (u << 5);
            const float4 f0 = *reinterpret_cast<const float4*>(rowp + c);
            const float4 f1 = *reinterpret_cast<const float4*>(rowp + c + 4);
            union { unsigned int u4[4]; short8 s; } pv;
            pv.u4[0] = pk2(f0.x, f0.y); pv.u4[1] = pk2(f0.z, f0.w);
            pv.u4[2] = pk2(f1.x, f1.y); pv.u4[3] = pk2(f1.z, f1.w);
            *reinterpret_cast<short8*>(&smem[XS(t, c)]) = pv.s;
        }
    }
    __syncthreads();   // the ONLY barrier in this kernel

    const f32x4 fz = {0.f, 0.f, 0.f, 0.f};
    const float SCL = 0.17677669529663687f * 1.4426950408889634f;  // scale*log2e

    // ===== phase 1: q,k joint GEMM (shared xf loads) =====
    // q,k[tok=tt*16+q16][d=dt*16+g*4+{0..3}]  via D = W·x^T
    uint2 pq[2][4], pkk[2][4];
    {
        f32x4 aq[2][4], ak[2][4];
        #pragma unroll
        for (int dt = 0; dt < 2; ++dt)
            #pragma unroll
            for (int tt = 0; tt < 4; ++tt) { aq[dt][tt] = fz; ak[dt][tt] = fz; }

        const unsigned short* wqb = wqkvT + (size_t)(h * 32) * 256;
        const unsigned short* wkb = wqkvT + (size_t)(256 + h * 32) * 256;
        #pragma unroll
        for (int ks = 0; ks < 8; ++ks) {
            const int kc = ks << 5;
            short8 xf[4];
            #pragma unroll
            for (int tt = 0; tt < 4; ++tt)
                xf[tt] = *reinterpret_cast<const short8*>(&smem[XS(tt * 16 + q16, kc + (g << 3))]);
            #pragma unroll
            for (int dt = 0; dt < 2; ++dt) {
                const size_t ro = (size_t)(dt * 16 + q16) * 256 + kc + (g << 3);
                const short8 wfq = *reinterpret_cast<const short8*>(wqb + ro);
                const short8 wfk = *reinterpret_cast<const short8*>(wkb + ro);
                #pragma unroll
                for (int tt = 0; tt < 4; ++tt) {
                    aq[dt][tt] = MFMA(wfq, xf[tt], aq[dt][tt]);
                    ak[dt][tt] = MFMA(wfk, xf[tt], ak[dt][tt]);
                }
            }
        }
        #pragma unroll
        for (int dt = 0; dt < 2; ++dt) {
            const float4 bbq = *reinterpret_cast<const float4*>(bqkv + h * 32 + dt * 16 + (g << 2));
            const float4 bbk = *reinterpret_cast<const float4*>(bqkv + 256 + h * 32 + dt * 16 + (g << 2));
            #pragma unroll
            for (int tt = 0; tt < 4; ++tt) {
                const f32x4 a = aq[dt][tt];
                pq[dt][tt]  = make_uint2(pk2((a[0] + bbq.x) * SCL, (a[1] + bbq.y) * SCL),
                                         pk2((a[2] + bbq.z) * SCL, (a[3] + bbq.w) * SCL));
                const f32x4 c = ak[dt][tt];
                pkk[dt][tt] = make_uint2(pk2(c[0] + bbk.x, c[1] + bbk.y),
                                         pk2(c[2] + bbk.z, c[3] + bbk.w));
            }
        }
    }

    // ===== phase 2: S^T = K·Q^T (K=16), exp2 (no max-sub), unnormalized P^T =====
    uint2 ppk[4][4];   // [kt][qt]: P^T[key=kt*16+g*4+{0..3}][qtok=qt*16+q16]
    float inv4[4];
    #pragma unroll
    for (int qt = 0; qt < 4; ++qt) {
        f32x4 st[4];
        #pragma unroll
        for (int kt = 0; kt < 4; ++kt) st[kt] = fz;
        #pragma unroll
        for (int dt = 0; dt < 2; ++dt)
            #pragma unroll
            for (int kt = 0; kt < 4; ++kt)
                st[kt] = mfma16(pkk[dt][kt], pq[dt][qt], st[kt]);
        float sum = 0.f;
        #pragma unroll
        for (int kt = 0; kt < 4; ++kt) {
            const float e0 = EXP2(st[kt][0]), e1 = EXP2(st[kt][1]);
            const float e2 = EXP2(st[kt][2]), e3 = EXP2(st[kt][3]);
            sum += (e0 + e1) + (e2 + e3);
            ppk[kt][qt] = make_uint2(pk2(e0, e1), pk2(e2, e3));
        }
        sum += __shfl_xor(sum, 16);
        sum += __shfl_xor(sum, 32);
        inv4[qt] = 1.f / sum;
    }

    // ===== phase 3: v GEMM (x_lds still intact) =====
    // v[tok=tt*16+g*4+{0..3}][d=dt*16+q16]  via D = x·W
    uint2 pv2[2][4];
    {
        f32x4 av[2][4];
        #pragma unroll
        for (int dt = 0; dt < 2; ++dt)
            #pragma unroll
            for (int tt = 0; tt < 4; ++tt) av[dt][tt] = fz;
        const unsigned short* wvb = wqkvT + (size_t)(512 + h * 32) * 256;
        #pragma unroll
        for (int ks = 0; ks < 8; ++ks) {
            const int kc = ks << 5;
            short8 xf[4];
            #pragma unroll
            for (int tt = 0; tt < 4; ++tt)
                xf[tt] = *reinterpret_cast<const short8*>(&smem[XS(tt * 16 + q16, kc + (g << 3))]);
            #pragma unroll
            for (int dt = 0; dt < 2; ++dt) {
                const short8 wf = *reinterpret_cast<const short8*>(
                    wvb + (size_t)(dt * 16 + q16) * 256 + kc + (g << 3));
                #pragma unroll
                for (int tt = 0; tt < 4; ++tt)
                    av[dt][tt] = MFMA(xf[tt], wf, av[dt][tt]);
            }
        }
        #pragma unroll
        for (int dt = 0; dt < 2; ++dt) {
            const float bv = bqkv[512 + h * 32 + dt * 16 + q16];
            #pragma unroll
            for (int tt = 0; tt < 4; ++tt) {
                const f32x4 a = av[dt][tt];
                pv2[dt][tt] = make_uint2(pk2(a[0] + bv, a[1] + bv),
                                         pk2(a[2] + bv, a[3] + bv));
            }
        }
    }

    // ===== phase 4: O^T = V^T·P^T (K=16) =====
    f32x4 ot[2][4];    // lane: O[tok=tt*16+q16][d=h*32+dt*16+g*4+r]
    #pragma unroll
    for (int dt = 0; dt < 2; ++dt)
        #pragma unroll
        for (int tt = 0; tt < 4; ++tt) ot[dt][tt] = fz;
    #pragma unroll
    for (int kt = 0; kt < 4; ++kt)
        #pragma unroll
        for (int tt = 0; tt < 4; ++tt)
            #pragma unroll
            for (int dt = 0; dt < 2; ++dt)
                ot[dt][tt] = mfma16(pv2[dt][kt], ppk[kt][tt], ot[dt][tt]);

    // ===== phase 5: direct global write of O (spatial row order) =====
    #pragma unroll
    for (int tt = 0; tt < 4; ++tt) {
        const float iv = inv4[tt];
        const int tok = tt * 16 + q16;
        const size_t srow = (((size_t)(b << 8) + (wh << 3) + (tok >> 3)) << 8)
                            + (ww << 3) + (tok & 7);
        unsigned short* drow = Ob + (srow << 8) + h * 32 + (g << 2);
        #pragma unroll
        for (int dt = 0; dt < 2; ++dt) {
            const uint2 pv = make_uint2(pk2(ot[dt][tt][0] * iv, ot[dt][tt][1] * iv),
                                        pk2(ot[dt][tt][2] * iv, ot[dt][tt][3] * iv));
            *reinterpret_cast<uint2*>(drow + dt * 16) = pv;
        }
    }
}

// ============ Kernel B: proj GEMM  out = O @ wproj + bias ============
__global__ __launch_bounds__(256, 2)
void proj_gemm(const unsigned short* __restrict__ Ob,
               const unsigned short* __restrict__ wprojT,
               const float* __restrict__ bproj,
               float* __restrict__ out)
{
    __shared__ unsigned short As[2][128 * 64];   // 16KB each
    __shared__ unsigned short Bs[2][128 * 64];

    const int tid  = threadIdx.x;
    const int wid  = tid >> 6;
    const int lane = tid & 63;
    const int g    = lane >> 4;
    const int q16  = lane & 15;
    const int wr   = wid >> 1, wc = wid & 1;

    // XCD-pairing swizzle: (mt, nt=0/1) pair shares the A-tile on one XCD
    const int bid = blockIdx.x;
    const int q   = bid >> 3;
    const int mt  = (bid & 7) * 256 + (q >> 1);
    const int nt  = q & 1;
    const size_t mrow0 = (size_t)mt << 7;
    const int nrow0 = nt << 7;

    const f32x4 fz = {0.f, 0.f, 0.f, 0.f};
    f32x4 acc[4][4];
    #pragma unroll
    for (int i = 0; i < 4; ++i)
        #pragma unroll
        for (int j = 0; j < 4; ++j) acc[i][j] = fz;

    int buf = 0;
    // prologue stage s=0
    #pragma unroll
    for (int i = 0; i < 4; ++i) {
        const int chunk = (i << 8) + tid;
        const int r = chunk >> 3, c = chunk & 7;
        const int cs = c ^ (r & 7);
        const uint4 va = *reinterpret_cast<const uint4*>(Ob + ((mrow0 + r) << 8) + (c << 3));
        *reinterpret_cast<uint4*>(&As[0][(r << 6) + (cs << 3)]) = va;
        const uint4 vb = *reinterpret_cast<const uint4*>(wprojT + ((size_t)(nrow0 + r) << 8) + (c << 3));
        *reinterpret_cast<uint4*>(&Bs[0][(r << 6) + (cs << 3)]) = vb;
    }
    __syncthreads();

    for (int s = 0; s < 4; ++s) {
        if (s < 3) {
            const int so = (s + 1) << 6;
            #pragma unroll
            for (int i = 0; i < 4; ++i) {
                const int chunk = (i << 8) + tid;
                const int r = chunk >> 3, c = chunk & 7;
                const int cs = c ^ (r & 7);
                const uint4 va = *reinterpret_cast<const uint4*>(Ob + ((mrow0 + r) << 8) + so + (c << 3));
                *reinterpret_cast<uint4*>(&As[buf ^ 1][(r << 6) + (cs << 3)]) = va;
                const uint4 vb = *reinterpret_cast<const uint4*>(wprojT + ((size_t)(nrow0 + r) << 8) + so + (c << 3));
                *reinterpret_cast<uint4*>(&Bs[buf ^ 1][(r << 6) + (cs << 3)]) = vb;
            }
        }
        #pragma unroll
        for (int kk = 0; kk < 2; ++kk) {
            short8 aF[4], bF[4];
            #pragma unroll
            for (int i = 0; i < 4; ++i) {
                const int rA = (wr << 6) + (i << 4) + q16;
                const int cA = ((kk << 2) + g) ^ (rA & 7);
                aF[i] = *reinterpret_cast<const short8*>(&As[buf][(rA << 6) + (cA << 3)]);
                const int rB = (wc << 6) + (i << 4) + q16;
                const int cB = ((kk << 2) + g) ^ (rB & 7);
                bF[i] = *reinterpret_cast<const short8*>(&Bs[buf][(rB << 6) + (cB << 3)]);
            }
            #pragma unroll
            for (int i = 0; i < 4; ++i)
                #pragma unroll
                for (int j = 0; j < 4; ++j)
                    acc[i][j] = MFMA(aF[i], bF[j], acc[i][j]);
        }
        __syncthreads();
        buf ^= 1;
    }

    // epilogue: rows are spatial order -> direct coalesced store
    #pragma unroll
    for (int j = 0; j < 4; ++j) {
        const int coln = nrow0 + (wc << 6) + (j << 4) + q16;
        const float bp = bproj[coln];
        #pragma unroll
        for (int i = 0; i < 4; ++i) {
            const size_t row = mrow0 + (wr << 6) + (i << 4) + (g << 2);
            #pragma unroll
            for (int rr = 0; rr < 4; ++rr)
                out[((row + rr) << 8) + coln] = acc[i][j][rr] + bp;
        }
    }
}

// ============ Fallback: R4 fused kernel (if ws too small) ============
__global__ __launch_bounds__(512, 2)
void winattn_fused(const float* __restrict__ x,
                   const float* __restrict__ bqkv,
                   const float* __restrict__ bproj,
                   const unsigned short* __restrict__ wqkvT,
                   const unsigned short* __restrict__ wprojT,
                   float* __restrict__ out)
{
    __shared__ unsigned short smem[64 * 256];

    const int tid  = threadIdx.x;
    const int h    = tid >> 6;
    const int lane = tid & 63;
    const int g    = lane >> 4;
    const int q16  = lane & 15;

    const int widx = blockIdx.x;
    const int b  = widx >> 10;
    const int wh = (widx >> 5) & 31;
    const int ww = widx & 31;

    {
        const int t  = tid >> 3;
        const int c0 = (tid & 7) << 3;
        const int hr = (wh << 3) + (t >> 3);
        const int wc = (ww << 3) + (t & 7);
        const float* rowp = x + (((size_t)b * 256 + hr) * 256 + wc) * 256;
        #pragma unroll
        for (int u = 0; u < 4; ++u) {
            const int c = c0 + (u << 6);
            const float4 f0 = *reinterpret_cast<const float4*>(rowp + c);
            const float4 f1 = *reinterpret_cast<const float4*>(rowp + c + 4);
            union { unsigned int u4[4]; short8 s; } pv;
            pv.u4[0] = pk2(f0.x, f0.y); pv.u4[1] = pk2(f0.z, f0.w);
            pv.u4[2] = pk2(f1.x, f1.y); pv.u4[3] = pk2(f1.z, f1.w);
            *reinterpret_cast<short8*>(&smem[XS(t, c)]) = pv.s;
        }
    }
    __syncthreads();

    const f32x4 fz = {0.f, 0.f, 0.f, 0.f};
    const float SCL = 0.17677669529663687f * 1.4426950408889634f;

    uint2 pk[3][2][4];
    #pragma unroll
    for (int m = 0; m < 3; ++m) {
        f32x4 acc[2][4];
        #pragma unroll
        for (int dt = 0; dt < 2; ++dt)
            #pragma unroll
            for (int tt = 0; tt < 4; ++tt) acc[dt][tt] = fz;
        const unsigned short* wb = wqkvT + (size_t)(m * 256 + h * 32) * 256;
        #pragma unroll
        for (int ks = 0; ks < 8; ++ks) {
            const int kc = ks << 5;
            short8 xf[4];
            #pragma unroll
            for (int tt = 0; tt < 4; ++tt)
                xf[tt] = *reinterpret_cast<const short8*>(&smem[XS(tt * 16 + q16, kc + (g << 3))]);
            #pragma unroll
            for (int dt = 0; dt < 2; ++dt) {
                const short8 wf = *reinterpret_cast<const short8*>(
                    wb + (size_t)(dt * 16 + q16) * 256 + kc + (g << 3));
                #pragma unroll
                for (int tt = 0; tt < 4; ++tt)
                    acc[dt][tt] = (m < 2) ? MFMA(wf, xf[tt], acc[dt][tt])
                                          : MFMA(xf[tt], wf, acc[dt][tt]);
            }
        }
        if (m < 2) {
            #pragma unroll
            for (int dt = 0; dt < 2; ++dt) {
                const float4 bb = *reinterpret_cast<const float4*>(
                    bqkv + m * 256 + h * 32 + dt * 16 + (g << 2));
                const float sc = (m == 0) ? SCL : 1.f;
                #pragma unroll
                for (int tt = 0; tt < 4; ++tt) {
                    const f32x4 a = acc[dt][tt];
                    pk[m][dt][tt] = make_uint2(pk2((a[0] + bb.x) * sc, (a[1] + bb.y) * sc),
                                               pk2((a[2] + bb.z) * sc, (a[3] + bb.w) * sc));
                }
            }
        } else {
            #pragma unroll
            for (int dt = 0; dt < 2; ++dt) {
                const float bv = bqkv[512 + h * 32 + dt * 16 + q16];
                #pragma unroll
                for (int tt = 0; tt < 4; ++tt) {
                    const f32x4 a = acc[dt][tt];
                    pk[2][dt][tt] = make_uint2(pk2(a[0] + bv, a[1] + bv),
                                               pk2(a[2] + bv, a[3] + bv));
                }
            }
        }
    }

    uint2 ppk[4][4];
    float inv4[4];
    #pragma unroll
    for (int qt = 0; qt < 4; ++qt) {
        f32x4 st[4];
        #pragma unroll
        for (int kt = 0; kt < 4; ++kt) st[kt] = fz;
        #pragma unroll
        for (int dt = 0; dt < 2; ++dt)
            #pragma unroll
            for (int kt = 0; kt < 4; ++kt)
                st[kt] = mfma16(pk[1][dt][kt], pk[0][dt][qt], st[kt]);
        float sum = 0.f;
        #pragma unroll
        for (int kt = 0; kt < 4; ++kt) {
            const float e0 = EXP2(st[kt][0]), e1 = EXP2(st[kt][1]);
            const float e2 = EXP2(st[kt][2]), e3 = EXP2(st[kt][3]);
            sum += (e0 + e1) + (e2 + e3);
            ppk[kt][qt] = make_uint2(pk2(e0, e1), pk2(e2, e3));
        }
        sum += __shfl_xor(sum, 16);
        sum += __shfl_xor(sum, 32);
        inv4[qt] = 1.f / sum;
    }

    f32x4 ot[2][4];
    #pragma unroll
    for (int dt = 0; dt < 2; ++dt)
        #pragma unroll
        for (int tt = 0; tt < 4; ++tt) ot[dt][tt] = fz;
    #pragma unroll
    for (int kt = 0; kt < 4; ++kt)
        #pragma unroll
        for (int tt = 0; tt < 4; ++tt)
            #pragma unroll
            for (int dt = 0; dt < 2; ++dt)
                ot[dt][tt] = mfma16(pk[2][dt][kt], ppk[kt][tt], ot[dt][tt]);

    __syncthreads();
    #pragma unroll
    for (int dt = 0; dt < 2; ++dt)
        #pragma unroll
        for (int tt = 0; tt < 4; ++tt) {
            const float iv = inv4[tt];
            const int tok = tt * 16 + q16;
            const int d   = h * 32 + dt * 16 + (g << 2);
            const uint2 pv = make_uint2(pk2(ot[dt][tt][0] * iv, ot[dt][tt][1] * iv),
                                        pk2(ot[dt][tt][2] * iv, ot[dt][tt][3] * iv));
            *reinterpret_cast<uint2*>(&smem[XS(tok, d)]) = pv;
        }
    __syncthreads();

    f32x4 pacc[4][2];
    #pragma unroll
    for (int mt = 0; mt < 4; ++mt)
        #pragma unroll
        for (int nt = 0; nt < 2; ++nt) pacc[mt][nt] = fz;
    #pragma unroll
    for (int ks = 0; ks < 8; ++ks) {
        const int kc = ks << 5;
        short8 of[4], wf[2];
        #pragma unroll
        for (int mt = 0; mt < 4; ++mt)
            of[mt] = *reinterpret_cast<const short8*>(&smem[XS(mt * 16 + q16, kc + (g << 3))]);
        #pragma unroll
        for (int nt = 0; nt < 2; ++nt)
            wf[nt] = *reinterpret_cast<const short8*>(
                wprojT + (size_t)(h * 32 + nt * 16 + q16) * 256 + kc + (g << 3));
        #pragma unroll
        for (int mt = 0; mt < 4; ++mt)
            #pragma unroll
            for (int nt = 0; nt < 2; ++nt)
                pacc[mt][nt] = MFMA(of[mt], wf[nt], pacc[mt][nt]);
    }
    {
        float bp[2];
        #pragma unroll
        for (int nt = 0; nt < 2; ++nt) bp[nt] = bproj[h * 32 + nt * 16 + q16];
        float* obase = out + (((size_t)b * 256 + (wh << 3) + (g >> 1)) * 256
                              + (ww << 3) + ((g & 1) << 2)) * 256 + h * 32 + q16;
        #pragma unroll
        for (int mt = 0; mt < 4; ++mt)
            #pragma unroll
            for (int r = 0; r < 4; ++r)
                #pragma unroll
                for (int nt = 0; nt < 2; ++nt)
                    obase[mt * 131072 + r * 256 + nt * 16] = pacc[mt][nt][r] + bp[nt];
    }
}

extern "C" void kernel_launch(void* const* d_in, const int* in_sizes, int n_in,
                              void* d_out, int out_size, void* d_ws, size_t ws_size,
                              hipStream_t stream) {
    const float* x     = (const float*)d_in[0];
    const float* wqkv  = (const float*)d_in[1];
    const float* bqkv  = (const float*)d_in[2];
    const float* wproj = (const float*)d_in[3];
    const float* bproj = (const float*)d_in[4];
    float* out = (float*)d_out;
    unsigned short* wT = (unsigned short*)d_ws;

    prep_w<<<1024, 256, 0, stream>>>(wqkv, wproj, wT);

    const size_t need = 524288ull + 262144ull * 256ull * 2ull;  // weights + O
    if (ws_size >= need) {
        unsigned short* Ob = wT + 262144;   // byte offset 524288
        attn_qkv<<<8192, 256, 0, stream>>>(x, bqkv, wT, Ob);
        proj_gemm<<<4096, 256, 0, stream>>>(Ob, wT + 768 * 256, bproj, out);
    } else {
        winattn_fused<<<4096, 512, 0, stream>>>(x, bqkv, bproj, wT, wT + 768 * 256, out);
    }
}